// Round 6
// baseline (479.474 us; speedup 1.0000x reference)
//
#include <hip/hip_runtime.h>
#include <math.h>

#define H_ 192
#define W_ 384
#define HW_ 73728

__device__ __forceinline__ float4 f4_relu_bn(float4 f, float s, float t) {
    return make_float4(fmaxf(fmaf(f.x, s, t), 0.0f), fmaxf(fmaf(f.y, s, t), 0.0f),
                       fmaxf(fmaf(f.z, s, t), 0.0f), fmaxf(fmaf(f.w, s, t), 0.0f));
}

// ---------------------------------------------------------------------------
// K1: unified q/k/v projection. grid (288, 6). blockIdx.y: 0=q,1=k,2..5=v[16ch].
// 2 pixels per thread (float2). Weights via uniform scalar loads (s_load) —
// no LDS broadcast in the inner loop.
// ---------------------------------------------------------------------------
__global__ __launch_bounds__(256) void k_proj6(
    const float* __restrict__ x,
    const float* __restrict__ wq, const float* __restrict__ bq,
    const float* __restrict__ wk, const float* __restrict__ bk,
    const float* __restrict__ wv, const float* __restrict__ bv,
    float* __restrict__ x1, float* __restrict__ x2, float* __restrict__ x3)
{
    int slab = blockIdx.y;
    const float* wsel; const float* bsel; float* db; int nch, off;
    if (slab == 0)      { wsel = wq; bsel = bq; db = x1; nch = 16; off = 0; }
    else if (slab == 1) { wsel = wk; bsel = bk; db = x2; nch = 16; off = 0; }
    else { int q = slab - 2; wsel = wv + q * 1024; bsel = bv + q * 16;
           db = x3; nch = 64; off = q * 16; }

    int tid = blockIdx.x * 256 + threadIdx.x;   // 0..73727
    int n  = tid / (HW_ / 2);
    int s2 = (tid - n * (HW_ / 2)) * 2;

    float2 acc[16];
#pragma unroll
    for (int o = 0; o < 16; o++) { float b = bsel[o]; acc[o] = make_float2(b, b); }

    const float* xp = x + n * (64 * HW_) + s2;
#pragma unroll 8
    for (int c = 0; c < 64; c++) {
        float2 xv = *(const float2*)(xp + c * HW_);
#pragma unroll
        for (int o = 0; o < 16; o++) {
            float w = wsel[o * 64 + c];           // uniform -> SGPR
            acc[o].x = fmaf(w, xv.x, acc[o].x);
            acc[o].y = fmaf(w, xv.y, acc[o].y);
        }
    }
    float* dp = db + (n * nch + off) * HW_ + s2;
#pragma unroll
    for (int o = 0; o < 16; o++) *(float2*)(dp + o * HW_) = acc[o];
}

// ---------------------------------------------------------------------------
// K2: g-projection, uniform scalar-load weights, no LDS.
// ---------------------------------------------------------------------------
__global__ __launch_bounds__(256) void k_proj_g(
    const float* __restrict__ g,
    const float* __restrict__ wg, const float* __restrict__ bg,
    float* __restrict__ gg)
{
    int p = blockIdx.x * 256 + threadIdx.x;
    int n = p / HW_, s = p - n * HW_;

    float a[16];
#pragma unroll
    for (int o = 0; o < 16; o++) a[o] = bg[o];

    const float* gp = g + n * (128 * HW_) + s;
#pragma unroll 8
    for (int c = 0; c < 128; c++) {
        float gv = gp[c * HW_];
#pragma unroll
        for (int o = 0; o < 16; o++) a[o] = fmaf(wg[o * 128 + c], gv, a[o]);
    }
#pragma unroll
    for (int o = 0; o < 16; o++) gg[(n * 16 + o) * HW_ + s] = a[o];
}

// ---------------------------------------------------------------------------
// K3: tap-parallel weight logits, 4 pixels/thread (float4).
// grid (144, 9): blockIdx.y = tap k. Neighbor vectors rebuilt from one
// aligned float4 + <=1 scalar; reflect padding as address/sign select.
// ---------------------------------------------------------------------------
struct WParams {
    const float *x1, *x2, *gg;
    const float *wp;
    const float *bn1g, *bn1b, *bn1m, *bn1v, *w1a;
    const float *bn2g, *bn2b, *bn2m, *bn2v, *w1b, *b1b;
    const float *bn3g, *bn3b, *bn3m, *bn3v, *w2a, *b2a;
    float *w1o, *w2o;   // [n][9][HW] raw logits
};

__global__ __launch_bounds__(256) void k_wtap4(WParams P)
{
    __shared__ float ls1[18], lt1[18], lw1a[288];
    __shared__ float ls2[16], lt2[16], lw1b[16];
    __shared__ float ls3[16], lt3[16], lw2a[16];
    __shared__ float lwp[4], lsc[2];

    int t = threadIdx.x;
    if (t < 18) {
        float sc = P.bn1g[t] * rsqrtf(P.bn1v[t] + 1e-5f);
        ls1[t] = sc; lt1[t] = P.bn1b[t] - P.bn1m[t] * sc;
    } else if (t >= 32 && t < 48) {
        int c = t - 32;
        float sc = P.bn2g[c] * rsqrtf(P.bn2v[c] + 1e-5f);
        ls2[c] = sc; lt2[c] = P.bn2b[c] - P.bn2m[c] * sc; lw1b[c] = P.w1b[c];
    } else if (t >= 64 && t < 80) {
        int c = t - 64;
        float sc = P.bn3g[c] * rsqrtf(P.bn3v[c] + 1e-5f);
        ls3[c] = sc; lt3[c] = P.bn3b[c] - P.bn3m[c] * sc; lw2a[c] = P.w2a[c];
    } else if (t >= 96 && t < 100) {
        lwp[t - 96] = P.wp[t - 96];
    } else if (t == 100) {
        lsc[0] = P.b1b[0]; lsc[1] = P.b2a[0];
    }
    for (int i = t; i < 288; i += 256) lw1a[i] = P.w1a[i];
    __syncthreads();

    int k  = blockIdx.y;          // 0..8, uniform
    int ki = k / 3, kj = k - ki * 3;

    int tid = blockIdx.x * 256 + t;              // 0..36863
    int n  = tid / (HW_ / 4);
    int r  = tid - n * (HW_ / 4);
    int hi = r / (W_ / 4);
    int w4 = (r - hi * (W_ / 4)) * 4;            // 0,4,...,380

    int hn = hi + ki - 1; hn = (hn < 0) ? -hn : ((hn >= H_) ? 2 * (H_ - 1) - hn : hn);
    int rowc = hi * W_ + w4;                     // center (aligned)
    int rown = hn * W_;                          // neighbor row base
    float dlh = (float)(hi - hn) * (2.0f / (H_ - 1));

    const float c_w = 2.0f / (W_ - 1);
    float4 dlw;
    {
        float v = -(float)(kj - 1) * c_w;
        dlw = make_float4(v, v, v, v);
        if (w4 == 0 && kj == 0)        dlw.x = -c_w;   // reflect: wn=1
        if (w4 == W_ - 4 && kj == 2)   dlw.w =  c_w;   // reflect: wn=382
    }
    int offL = (w4 == 0)      ? rown + 1        : rown + w4 - 1;
    int offR = (w4 == W_ - 4) ? rown + W_ - 2   : rown + w4 + 4;

    const float* x1p = P.x1 + n * (16 * HW_);
    const float* x2p = P.x2 + n * (16 * HW_);
    const float* ggp = P.gg + n * (16 * HW_);

    float4 h1[16];
#pragma unroll
    for (int o = 0; o < 16; o++) h1[o] = make_float4(0.f, 0.f, 0.f, 0.f);

#pragma unroll
    for (int c = 0; c < 16; c++) {
        const float* pl = x2p + c * HW_;
        float4 a = *(const float4*)(pl + rown + w4);
        float4 nb;
        if (kj == 0)      nb = make_float4(pl[offL], a.x, a.y, a.z);
        else if (kj == 1) nb = a;
        else              nb = make_float4(a.y, a.z, a.w, pl[offR]);
        float4 cen = *(const float4*)(x1p + c * HW_ + rowc);
        float4 f = make_float4(cen.x - nb.x, cen.y - nb.y, cen.z - nb.z, cen.w - nb.w);
        f = f4_relu_bn(f, ls1[c], lt1[c]);
#pragma unroll
        for (int o = 0; o < 16; o++) {
            float w = lw1a[o * 18 + c];
            h1[o].x = fmaf(w, f.x, h1[o].x);
            h1[o].y = fmaf(w, f.y, h1[o].y);
            h1[o].z = fmaf(w, f.z, h1[o].z);
            h1[o].w = fmaf(w, f.w, h1[o].w);
        }
    }
#pragma unroll
    for (int pc = 0; pc < 2; pc++) {
        float wx = lwp[pc * 2 + 0], wy = lwp[pc * 2 + 1];
        float4 f = make_float4(fmaf(wx, dlw.x, wy * dlh), fmaf(wx, dlw.y, wy * dlh),
                               fmaf(wx, dlw.z, wy * dlh), fmaf(wx, dlw.w, wy * dlh));
        f = f4_relu_bn(f, ls1[16 + pc], lt1[16 + pc]);
#pragma unroll
        for (int o = 0; o < 16; o++) {
            float w = lw1a[o * 18 + 16 + pc];
            h1[o].x = fmaf(w, f.x, h1[o].x);
            h1[o].y = fmaf(w, f.y, h1[o].y);
            h1[o].z = fmaf(w, f.z, h1[o].z);
            h1[o].w = fmaf(w, f.w, h1[o].w);
        }
    }
    float4 l1 = make_float4(lsc[0], lsc[0], lsc[0], lsc[0]);
#pragma unroll
    for (int o = 0; o < 16; o++) {
        float4 v = f4_relu_bn(h1[o], ls2[o], lt2[o]);
        float w = lw1b[o];
        l1.x = fmaf(w, v.x, l1.x); l1.y = fmaf(w, v.y, l1.y);
        l1.z = fmaf(w, v.z, l1.z); l1.w = fmaf(w, v.w, l1.w);
    }

    float4 l2 = make_float4(lsc[1], lsc[1], lsc[1], lsc[1]);
#pragma unroll
    for (int c = 0; c < 16; c++) {
        const float* pl = ggp + c * HW_;
        float4 a = *(const float4*)(pl + rown + w4);
        float4 nb;
        if (kj == 0)      nb = make_float4(pl[offL], a.x, a.y, a.z);
        else if (kj == 1) nb = a;
        else              nb = make_float4(a.y, a.z, a.w, pl[offR]);
        float4 cen = *(const float4*)(pl + rowc);
        float4 f = make_float4(cen.x - nb.x, cen.y - nb.y, cen.z - nb.z, cen.w - nb.w);
        f = f4_relu_bn(f, ls3[c], lt3[c]);
        float w = lw2a[c];
        l2.x = fmaf(w, f.x, l2.x); l2.y = fmaf(w, f.y, l2.y);
        l2.z = fmaf(w, f.z, l2.z); l2.w = fmaf(w, f.w, l2.w);
    }

    *(float4*)(P.w1o + (n * 9 + k) * HW_ + rowc) = l1;
    *(float4*)(P.w2o + (n * 9 + k) * HW_ + rowc) = l2;
}

// ---------------------------------------------------------------------------
// K4: pixel-vectorized 9-tap aggregation + in-register softmax (unchanged).
// ---------------------------------------------------------------------------
__global__ __launch_bounds__(256) void k_agg4(
    const float* __restrict__ src, const float* __restrict__ wlog,
    float* __restrict__ dst)
{
    int tid = blockIdx.x * 256 + threadIdx.x;        // span id, 36864 total
    int cb  = blockIdx.y;
    int n   = tid / (HW_ / 4);
    int r   = tid - n * (HW_ / 4);
    int hi  = r / (W_ / 4);
    int w4  = (r - hi * (W_ / 4)) * 4;

    int h0 = (hi == 0) ? 1 : hi - 1;
    int h2 = (hi == H_ - 1) ? H_ - 2 : hi + 1;
    int rows0 = h0 * W_, rows1 = hi * W_, rows2 = h2 * W_;

    int offL = (w4 == 0)   ? 1   : w4 - 1;
    int offR = (w4 == 380) ? 382 : w4 + 4;

    const float* wl = wlog + n * 9 * HW_ + rows1 + w4;
    float4 wv[9];
#pragma unroll
    for (int k = 0; k < 9; k++) wv[k] = *(const float4*)(wl + k * HW_);
    float4 m = wv[0];
#pragma unroll
    for (int k = 1; k < 9; k++) {
        m.x = fmaxf(m.x, wv[k].x); m.y = fmaxf(m.y, wv[k].y);
        m.z = fmaxf(m.z, wv[k].z); m.w = fmaxf(m.w, wv[k].w);
    }
    float4 sum = make_float4(0.f, 0.f, 0.f, 0.f);
#pragma unroll
    for (int k = 0; k < 9; k++) {
        wv[k].x = __expf(wv[k].x - m.x); sum.x += wv[k].x;
        wv[k].y = __expf(wv[k].y - m.y); sum.y += wv[k].y;
        wv[k].z = __expf(wv[k].z - m.z); sum.z += wv[k].z;
        wv[k].w = __expf(wv[k].w - m.w); sum.w += wv[k].w;
    }
    float4 inv = make_float4(1.f / sum.x, 1.f / sum.y, 1.f / sum.z, 1.f / sum.w);
#pragma unroll
    for (int k = 0; k < 9; k++) {
        wv[k].x *= inv.x; wv[k].y *= inv.y; wv[k].z *= inv.z; wv[k].w *= inv.w;
    }

    const float* srcn = src + n * (64 * HW_);
    float* dstn = dst + n * (64 * HW_) + rows1 + w4;

#pragma unroll 4
    for (int ci = 0; ci < 16; ci++) {
        int c = cb * 16 + ci;
        const float* sp = srcn + c * HW_;
        float4 acc = make_float4(0.f, 0.f, 0.f, 0.f);
        int rr[3] = {rows0, rows1, rows2};
#pragma unroll
        for (int krow = 0; krow < 3; krow++) {
            const float* rowp = sp + rr[krow];
            float4 cv = *(const float4*)(rowp + w4);
            float  lf = rowp[offL];
            float  rt = rowp[offR];
            float4 wL = wv[krow * 3 + 0];
            float4 wC = wv[krow * 3 + 1];
            float4 wR = wv[krow * 3 + 2];
            acc.x = fmaf(wL.x, lf,   acc.x);
            acc.y = fmaf(wL.y, cv.x, acc.y);
            acc.z = fmaf(wL.z, cv.y, acc.z);
            acc.w = fmaf(wL.w, cv.z, acc.w);
            acc.x = fmaf(wC.x, cv.x, acc.x);
            acc.y = fmaf(wC.y, cv.y, acc.y);
            acc.z = fmaf(wC.z, cv.z, acc.z);
            acc.w = fmaf(wC.w, cv.w, acc.w);
            acc.x = fmaf(wR.x, cv.y, acc.x);
            acc.y = fmaf(wR.y, cv.z, acc.y);
            acc.z = fmaf(wR.z, cv.w, acc.z);
            acc.w = fmaf(wR.w, rt,   acc.w);
        }
        *(float4*)(dstn + c * HW_) = acc;
    }
}

// ---------------------------------------------------------------------------
extern "C" void kernel_launch(void* const* d_in, const int* in_sizes, int n_in,
                              void* d_out, int out_size, void* d_ws, size_t ws_size,
                              hipStream_t stream)
{
    const float* x    = (const float*)d_in[0];
    const float* g    = (const float*)d_in[1];
    const float* w_q  = (const float*)d_in[2];
    const float* b_q  = (const float*)d_in[3];
    const float* w_k  = (const float*)d_in[4];
    const float* b_k  = (const float*)d_in[5];
    const float* w_v  = (const float*)d_in[6];
    const float* b_v  = (const float*)d_in[7];
    const float* w_g  = (const float*)d_in[8];
    const float* b_g  = (const float*)d_in[9];
    const float* w_p  = (const float*)d_in[10];
    // d_in[11] = b_p (cancels in center-minus-neighbor subtraction)
    const float* bn1g = (const float*)d_in[12];
    const float* bn1b = (const float*)d_in[13];
    const float* bn1m = (const float*)d_in[14];
    const float* bn1v = (const float*)d_in[15];
    const float* w1a  = (const float*)d_in[16];
    const float* bn2g = (const float*)d_in[17];
    const float* bn2b = (const float*)d_in[18];
    const float* bn2m = (const float*)d_in[19];
    const float* bn2v = (const float*)d_in[20];
    const float* w1b  = (const float*)d_in[21];
    const float* b1b  = (const float*)d_in[22];
    const float* bn3g = (const float*)d_in[23];
    const float* bn3b = (const float*)d_in[24];
    const float* bn3m = (const float*)d_in[25];
    const float* bn3v = (const float*)d_in[26];
    const float* w2a  = (const float*)d_in[27];
    const float* b2a  = (const float*)d_in[28];

    float* ws    = (float*)d_ws;
    float* x1    = ws;                     // 2*16*HW = 2359296 f
    float* x2    = x1 + 2359296;           // 2359296 f
    float* gg    = x2 + 2359296;           // 2359296 f
    float* out1  = gg + 2359296;           // 2*64*HW = 9437184 f
    float* w1log = out1 + 9437184;         // 2*9*HW = 1327104 f
    float* w2log = w1log + 1327104;        // 1327104 f   (total ~76.7 MB)
    float* x3    = (float*)d_out;          // d_out doubles as x3 scratch

    k_proj6<<<dim3(288, 6), 256, 0, stream>>>(x, w_q, b_q, w_k, b_k, w_v, b_v, x1, x2, x3);
    k_proj_g<<<576, 256, 0, stream>>>(g, w_g, b_g, gg);

    WParams P;
    P.x1 = x1; P.x2 = x2; P.gg = gg;
    P.wp = w_p;
    P.bn1g = bn1g; P.bn1b = bn1b; P.bn1m = bn1m; P.bn1v = bn1v; P.w1a = w1a;
    P.bn2g = bn2g; P.bn2b = bn2b; P.bn2m = bn2m; P.bn2v = bn2v; P.w1b = w1b; P.b1b = b1b;
    P.bn3g = bn3g; P.bn3b = bn3b; P.bn3m = bn3m; P.bn3v = bn3v; P.w2a = w2a; P.b2a = b2a;
    P.w1o = w1log; P.w2o = w2log;
    k_wtap4<<<dim3(144, 9), 256, 0, stream>>>(P);

    k_agg4<<<dim3(144, 4), 256, 0, stream>>>(x3, w1log, out1);            // agg1
    k_agg4<<<dim3(144, 4), 256, 0, stream>>>(out1, w2log, (float*)d_out); // agg2
}

// Round 7
// 178.489 us; speedup vs baseline: 2.6863x; 2.6863x over previous
//
#include <hip/hip_runtime.h>
#include <math.h>

#define H_ 192
#define W_ 384
#define HW_ 73728

// ---------------------------------------------------------------------------
// K0: fold BN constants once.  prep layout (floats):
// [0..17] s1, [18..35] t1, [36..51] s2, [52..67] t2, [68..83] s3, [84..99] t3
// ---------------------------------------------------------------------------
__global__ void k_prep(
    const float* __restrict__ bn1g, const float* __restrict__ bn1b,
    const float* __restrict__ bn1m, const float* __restrict__ bn1v,
    const float* __restrict__ bn2g, const float* __restrict__ bn2b,
    const float* __restrict__ bn2m, const float* __restrict__ bn2v,
    const float* __restrict__ bn3g, const float* __restrict__ bn3b,
    const float* __restrict__ bn3m, const float* __restrict__ bn3v,
    float* __restrict__ prep)
{
    int t = threadIdx.x;
    if (t < 18) {
        float sc = bn1g[t] * rsqrtf(bn1v[t] + 1e-5f);
        prep[t] = sc; prep[18 + t] = bn1b[t] - bn1m[t] * sc;
    } else if (t >= 32 && t < 48) {
        int c = t - 32;
        float sc = bn2g[c] * rsqrtf(bn2v[c] + 1e-5f);
        prep[36 + c] = sc; prep[52 + c] = bn2b[c] - bn2m[c] * sc;
    } else if (t >= 64 && t < 80) {
        int c = t - 64;
        float sc = bn3g[c] * rsqrtf(bn3v[c] + 1e-5f);
        prep[68 + c] = sc; prep[84 + c] = bn3b[c] - bn3m[c] * sc;
    }
}

// ---------------------------------------------------------------------------
// K1: unified q/k/v projection. grid (288, 6). blockIdx.y: 0=q,1=k,2..5=v[16ch].
// 2 pixels per thread (float2). Weights via uniform scalar loads.
// ---------------------------------------------------------------------------
__global__ __launch_bounds__(256) void k_proj6(
    const float* __restrict__ x,
    const float* __restrict__ wq, const float* __restrict__ bq,
    const float* __restrict__ wk, const float* __restrict__ bk,
    const float* __restrict__ wv, const float* __restrict__ bv,
    float* __restrict__ x1, float* __restrict__ x2, float* __restrict__ x3)
{
    int slab = blockIdx.y;
    const float* wsel; const float* bsel; float* db; int nch, off;
    if (slab == 0)      { wsel = wq; bsel = bq; db = x1; nch = 16; off = 0; }
    else if (slab == 1) { wsel = wk; bsel = bk; db = x2; nch = 16; off = 0; }
    else { int q = slab - 2; wsel = wv + q * 1024; bsel = bv + q * 16;
           db = x3; nch = 64; off = q * 16; }

    int tid = blockIdx.x * 256 + threadIdx.x;   // 0..73727
    int n  = tid / (HW_ / 2);
    int s2 = (tid - n * (HW_ / 2)) * 2;

    float2 acc[16];
#pragma unroll
    for (int o = 0; o < 16; o++) { float b = bsel[o]; acc[o] = make_float2(b, b); }

    const float* xp = x + n * (64 * HW_) + s2;
#pragma unroll 8
    for (int c = 0; c < 64; c++) {
        float2 xv = *(const float2*)(xp + c * HW_);
#pragma unroll
        for (int o = 0; o < 16; o++) {
            float w = wsel[o * 64 + c];           // uniform -> SGPR
            acc[o].x = fmaf(w, xv.x, acc[o].x);
            acc[o].y = fmaf(w, xv.y, acc[o].y);
        }
    }
    float* dp = db + (n * nch + off) * HW_ + s2;
#pragma unroll
    for (int o = 0; o < 16; o++) *(float2*)(dp + o * HW_) = acc[o];
}

// ---------------------------------------------------------------------------
// K2: g-projection, uniform scalar-load weights, no LDS.
// ---------------------------------------------------------------------------
__global__ __launch_bounds__(256) void k_proj_g(
    const float* __restrict__ g,
    const float* __restrict__ wg, const float* __restrict__ bg,
    float* __restrict__ gg)
{
    int p = blockIdx.x * 256 + threadIdx.x;
    int n = p / HW_, s = p - n * HW_;

    float a[16];
#pragma unroll
    for (int o = 0; o < 16; o++) a[o] = bg[o];

    const float* gp = g + n * (128 * HW_) + s;
#pragma unroll 8
    for (int c = 0; c < 128; c++) {
        float gv = gp[c * HW_];
#pragma unroll
        for (int o = 0; o < 16; o++) a[o] = fmaf(wg[o * 128 + c], gv, a[o]);
    }
#pragma unroll
    for (int o = 0; o < 16; o++) gg[(n * 16 + o) * HW_ + s] = a[o];
}

// ---------------------------------------------------------------------------
// K3: tap-parallel weight logits, scalar 1 px/thread, ZERO LDS.
// grid (576, 9). All weights/constants via uniform global reads (s_load).
// ---------------------------------------------------------------------------
struct WParams {
    const float *x1, *x2, *gg;
    const float *wp;
    const float *w1a, *w1b, *b1b, *w2a, *b2a;
    const float *prep;
    float *w1o, *w2o;   // [n][9][HW] raw logits
};

__global__ __launch_bounds__(256) void k_wtap_s(WParams P)
{
    const float* pr = P.prep;

    int k  = blockIdx.y;          // 0..8, uniform
    int ki = k / 3, kj = k - ki * 3;

    int p = blockIdx.x * 256 + threadIdx.x;
    int n = p / HW_, s = p - n * HW_;
    int hi = s / W_, wi = s - hi * W_;

    int hn = hi + ki - 1; hn = (hn < 0) ? -hn : ((hn >= H_) ? 2 * (H_ - 1) - hn : hn);
    int wn = wi + kj - 1; wn = (wn < 0) ? -wn : ((wn >= W_) ? 2 * (W_ - 1) - wn : wn);
    int snk = hn * W_ + wn;
    float dlh = (float)(hi - hn) * (2.0f / (H_ - 1));
    float dlw = (float)(wi - wn) * (2.0f / (W_ - 1));

    const float* x1p = P.x1 + n * (16 * HW_) + s;
    const float* x2p = P.x2 + n * (16 * HW_) + snk;
    const float* ggc = P.gg + n * (16 * HW_) + s;
    const float* ggn = P.gg + n * (16 * HW_) + snk;

    float h1[16];
#pragma unroll
    for (int o = 0; o < 16; o++) h1[o] = 0.0f;

#pragma unroll
    for (int c = 0; c < 16; c++) {
        float f = x1p[c * HW_] - x2p[c * HW_];
        f = fmaxf(fmaf(f, pr[c], pr[18 + c]), 0.0f);
#pragma unroll
        for (int o = 0; o < 16; o++) h1[o] = fmaf(P.w1a[o * 18 + c], f, h1[o]);
    }
#pragma unroll
    for (int pc = 0; pc < 2; pc++) {
        float f = P.wp[pc * 2 + 0] * dlw + P.wp[pc * 2 + 1] * dlh;
        f = fmaxf(fmaf(f, pr[16 + pc], pr[34 + pc]), 0.0f);
#pragma unroll
        for (int o = 0; o < 16; o++) h1[o] = fmaf(P.w1a[o * 18 + 16 + pc], f, h1[o]);
    }
    float l1 = P.b1b[0];
#pragma unroll
    for (int o = 0; o < 16; o++) {
        float v = fmaxf(fmaf(h1[o], pr[36 + o], pr[52 + o]), 0.0f);
        l1 = fmaf(P.w1b[o], v, l1);
    }

    float l2 = P.b2a[0];
#pragma unroll
    for (int c = 0; c < 16; c++) {
        float f = ggc[c * HW_] - ggn[c * HW_];
        f = fmaxf(fmaf(f, pr[68 + c], pr[84 + c]), 0.0f);
        l2 = fmaf(P.w2a[c], f, l2);
    }

    P.w1o[(n * 9 + k) * HW_ + s] = l1;
    P.w2o[(n * 9 + k) * HW_ + s] = l2;
}

// ---------------------------------------------------------------------------
// K4: pixel-vectorized 9-tap aggregation + in-register softmax.
// ---------------------------------------------------------------------------
__global__ __launch_bounds__(256) void k_agg4(
    const float* __restrict__ src, const float* __restrict__ wlog,
    float* __restrict__ dst)
{
    int tid = blockIdx.x * 256 + threadIdx.x;        // span id, 36864 total
    int cb  = blockIdx.y;
    int n   = tid / (HW_ / 4);
    int r   = tid - n * (HW_ / 4);
    int hi  = r / (W_ / 4);
    int w4  = (r - hi * (W_ / 4)) * 4;

    int h0 = (hi == 0) ? 1 : hi - 1;
    int h2 = (hi == H_ - 1) ? H_ - 2 : hi + 1;
    int rows0 = h0 * W_, rows1 = hi * W_, rows2 = h2 * W_;

    int offL = (w4 == 0)   ? 1   : w4 - 1;
    int offR = (w4 == 380) ? 382 : w4 + 4;

    const float* wl = wlog + n * 9 * HW_ + rows1 + w4;
    float4 wv[9];
#pragma unroll
    for (int k = 0; k < 9; k++) wv[k] = *(const float4*)(wl + k * HW_);
    float4 m = wv[0];
#pragma unroll
    for (int k = 1; k < 9; k++) {
        m.x = fmaxf(m.x, wv[k].x); m.y = fmaxf(m.y, wv[k].y);
        m.z = fmaxf(m.z, wv[k].z); m.w = fmaxf(m.w, wv[k].w);
    }
    float4 sum = make_float4(0.f, 0.f, 0.f, 0.f);
#pragma unroll
    for (int k = 0; k < 9; k++) {
        wv[k].x = __expf(wv[k].x - m.x); sum.x += wv[k].x;
        wv[k].y = __expf(wv[k].y - m.y); sum.y += wv[k].y;
        wv[k].z = __expf(wv[k].z - m.z); sum.z += wv[k].z;
        wv[k].w = __expf(wv[k].w - m.w); sum.w += wv[k].w;
    }
    float4 inv = make_float4(1.f / sum.x, 1.f / sum.y, 1.f / sum.z, 1.f / sum.w);
#pragma unroll
    for (int k = 0; k < 9; k++) {
        wv[k].x *= inv.x; wv[k].y *= inv.y; wv[k].z *= inv.z; wv[k].w *= inv.w;
    }

    const float* srcn = src + n * (64 * HW_);
    float* dstn = dst + n * (64 * HW_) + rows1 + w4;

#pragma unroll 4
    for (int ci = 0; ci < 16; ci++) {
        int c = cb * 16 + ci;
        const float* sp = srcn + c * HW_;
        float4 acc = make_float4(0.f, 0.f, 0.f, 0.f);
        int rr[3] = {rows0, rows1, rows2};
#pragma unroll
        for (int krow = 0; krow < 3; krow++) {
            const float* rowp = sp + rr[krow];
            float4 cv = *(const float4*)(rowp + w4);
            float  lf = rowp[offL];
            float  rt = rowp[offR];
            float4 wL = wv[krow * 3 + 0];
            float4 wC = wv[krow * 3 + 1];
            float4 wR = wv[krow * 3 + 2];
            acc.x = fmaf(wL.x, lf,   acc.x);
            acc.y = fmaf(wL.y, cv.x, acc.y);
            acc.z = fmaf(wL.z, cv.y, acc.z);
            acc.w = fmaf(wL.w, cv.z, acc.w);
            acc.x = fmaf(wC.x, cv.x, acc.x);
            acc.y = fmaf(wC.y, cv.y, acc.y);
            acc.z = fmaf(wC.z, cv.z, acc.z);
            acc.w = fmaf(wC.w, cv.w, acc.w);
            acc.x = fmaf(wR.x, cv.y, acc.x);
            acc.y = fmaf(wR.y, cv.z, acc.y);
            acc.z = fmaf(wR.z, cv.w, acc.z);
            acc.w = fmaf(wR.w, rt,   acc.w);
        }
        *(float4*)(dstn + c * HW_) = acc;
    }
}

// ---------------------------------------------------------------------------
extern "C" void kernel_launch(void* const* d_in, const int* in_sizes, int n_in,
                              void* d_out, int out_size, void* d_ws, size_t ws_size,
                              hipStream_t stream)
{
    const float* x    = (const float*)d_in[0];
    const float* g    = (const float*)d_in[1];
    const float* w_q  = (const float*)d_in[2];
    const float* b_q  = (const float*)d_in[3];
    const float* w_k  = (const float*)d_in[4];
    const float* b_k  = (const float*)d_in[5];
    const float* w_v  = (const float*)d_in[6];
    const float* b_v  = (const float*)d_in[7];
    const float* w_g  = (const float*)d_in[8];
    const float* b_g  = (const float*)d_in[9];
    const float* w_p  = (const float*)d_in[10];
    // d_in[11] = b_p (cancels in center-minus-neighbor subtraction)
    const float* bn1g = (const float*)d_in[12];
    const float* bn1b = (const float*)d_in[13];
    const float* bn1m = (const float*)d_in[14];
    const float* bn1v = (const float*)d_in[15];
    const float* w1a  = (const float*)d_in[16];
    const float* bn2g = (const float*)d_in[17];
    const float* bn2b = (const float*)d_in[18];
    const float* bn2m = (const float*)d_in[19];
    const float* bn2v = (const float*)d_in[20];
    const float* w1b  = (const float*)d_in[21];
    const float* b1b  = (const float*)d_in[22];
    const float* bn3g = (const float*)d_in[23];
    const float* bn3b = (const float*)d_in[24];
    const float* bn3m = (const float*)d_in[25];
    const float* bn3v = (const float*)d_in[26];
    const float* w2a  = (const float*)d_in[27];
    const float* b2a  = (const float*)d_in[28];

    float* ws    = (float*)d_ws;
    float* x1    = ws;                     // 2*16*HW = 2359296 f
    float* x2    = x1 + 2359296;           // 2359296 f
    float* gg    = x2 + 2359296;           // 2359296 f
    float* out1  = gg + 2359296;           // 2*64*HW = 9437184 f
    float* w1log = out1 + 9437184;         // 2*9*HW = 1327104 f
    float* w2log = w1log + 1327104;        // 1327104 f
    float* prep  = w2log + 1327104;        // 100 f  (total ~76.7 MB)
    float* x3    = (float*)d_out;          // d_out doubles as x3 scratch

    k_prep<<<1, 128, 0, stream>>>(bn1g, bn1b, bn1m, bn1v,
                                  bn2g, bn2b, bn2m, bn2v,
                                  bn3g, bn3b, bn3m, bn3v, prep);

    k_proj6<<<dim3(288, 6), 256, 0, stream>>>(x, w_q, b_q, w_k, b_k, w_v, b_v, x1, x2, x3);
    k_proj_g<<<576, 256, 0, stream>>>(g, w_g, b_g, gg);

    WParams P;
    P.x1 = x1; P.x2 = x2; P.gg = gg;
    P.wp = w_p;
    P.w1a = w1a; P.w1b = w1b; P.b1b = b1b; P.w2a = w2a; P.b2a = b2a;
    P.prep = prep;
    P.w1o = w1log; P.w2o = w2log;
    k_wtap_s<<<dim3(576, 9), 256, 0, stream>>>(P);

    k_agg4<<<dim3(144, 4), 256, 0, stream>>>(x3, w1log, out1);            // agg1
    k_agg4<<<dim3(144, 4), 256, 0, stream>>>(out1, w2log, (float*)d_out); // agg2
}

// Round 8
// 168.864 us; speedup vs baseline: 2.8394x; 1.0570x over previous
//
#include <hip/hip_runtime.h>
#include <math.h>

#define H_ 192
#define W_ 384
#define HW_ 73728

// ---------------------------------------------------------------------------
// K0: fold BN constants once.  prep layout (floats):
// [0..17] s1, [18..35] t1, [36..51] s2, [52..67] t2, [68..83] s3, [84..99] t3
// ---------------------------------------------------------------------------
__global__ void k_prep(
    const float* __restrict__ bn1g, const float* __restrict__ bn1b,
    const float* __restrict__ bn1m, const float* __restrict__ bn1v,
    const float* __restrict__ bn2g, const float* __restrict__ bn2b,
    const float* __restrict__ bn2m, const float* __restrict__ bn2v,
    const float* __restrict__ bn3g, const float* __restrict__ bn3b,
    const float* __restrict__ bn3m, const float* __restrict__ bn3v,
    float* __restrict__ prep)
{
    int t = threadIdx.x;
    if (t < 18) {
        float sc = bn1g[t] * rsqrtf(bn1v[t] + 1e-5f);
        prep[t] = sc; prep[18 + t] = bn1b[t] - bn1m[t] * sc;
    } else if (t >= 32 && t < 48) {
        int c = t - 32;
        float sc = bn2g[c] * rsqrtf(bn2v[c] + 1e-5f);
        prep[36 + c] = sc; prep[52 + c] = bn2b[c] - bn2m[c] * sc;
    } else if (t >= 64 && t < 80) {
        int c = t - 64;
        float sc = bn3g[c] * rsqrtf(bn3v[c] + 1e-5f);
        prep[68 + c] = sc; prep[84 + c] = bn3b[c] - bn3m[c] * sc;
    }
}

// ---------------------------------------------------------------------------
// K1: unified q/k/v projection. grid (288, 6). blockIdx.y: 0=q,1=k,2..5=v[16ch].
// 2 px/thread (float2); K-loop in batches of 8 with explicit prefetch array
// so 8 loads are in flight before the FMA block (MLP, no spill: ~56 VGPR).
// Weights via uniform scalar loads (SGPR operands).
// ---------------------------------------------------------------------------
__global__ __launch_bounds__(256) void k_proj6(
    const float* __restrict__ x,
    const float* __restrict__ wq, const float* __restrict__ bq,
    const float* __restrict__ wk, const float* __restrict__ bk,
    const float* __restrict__ wv, const float* __restrict__ bv,
    float* __restrict__ x1, float* __restrict__ x2, float* __restrict__ x3)
{
    int slab = blockIdx.y;
    const float* wsel; const float* bsel; float* db; int nch, off;
    if (slab == 0)      { wsel = wq; bsel = bq; db = x1; nch = 16; off = 0; }
    else if (slab == 1) { wsel = wk; bsel = bk; db = x2; nch = 16; off = 0; }
    else { int q = slab - 2; wsel = wv + q * 1024; bsel = bv + q * 16;
           db = x3; nch = 64; off = q * 16; }

    int tid = blockIdx.x * 256 + threadIdx.x;   // 0..73727
    int n  = tid / (HW_ / 2);
    int s2 = (tid - n * (HW_ / 2)) * 2;

    float2 acc[16];
#pragma unroll
    for (int o = 0; o < 16; o++) { float b = bsel[o]; acc[o] = make_float2(b, b); }

    const float* xp = x + n * (64 * HW_) + s2;
#pragma unroll 1
    for (int c0 = 0; c0 < 64; c0 += 8) {
        float2 v[8];
#pragma unroll
        for (int j = 0; j < 8; j++) v[j] = *(const float2*)(xp + (c0 + j) * HW_);
#pragma unroll
        for (int j = 0; j < 8; j++) {
#pragma unroll
            for (int o = 0; o < 16; o++) {
                float w = wsel[o * 64 + c0 + j];      // uniform -> SGPR
                acc[o].x = fmaf(w, v[j].x, acc[o].x);
                acc[o].y = fmaf(w, v[j].y, acc[o].y);
            }
        }
    }
    float* dp = db + (n * nch + off) * HW_ + s2;
#pragma unroll
    for (int o = 0; o < 16; o++) *(float2*)(dp + o * HW_) = acc[o];
}

// ---------------------------------------------------------------------------
// K2: g-projection. grid (288, 2): blockIdx.y = 8-output-channel half.
// 2 px/thread (float2); batches of 16 prefetched loads (MLP). g is read
// twice chip-wide but the second pass hits L3.
// ---------------------------------------------------------------------------
__global__ __launch_bounds__(256) void k_proj_g(
    const float* __restrict__ g,
    const float* __restrict__ wg, const float* __restrict__ bg,
    float* __restrict__ gg)
{
    int ob = blockIdx.y * 8;                    // output channel base
    int tid = blockIdx.x * 256 + threadIdx.x;   // 0..73727
    int n  = tid / (HW_ / 2);
    int s2 = (tid - n * (HW_ / 2)) * 2;

    float2 a[8];
#pragma unroll
    for (int o = 0; o < 8; o++) { float b = bg[ob + o]; a[o] = make_float2(b, b); }

    const float* gp = g + n * (128 * HW_) + s2;
#pragma unroll 1
    for (int c0 = 0; c0 < 128; c0 += 16) {
        float2 v[16];
#pragma unroll
        for (int j = 0; j < 16; j++) v[j] = *(const float2*)(gp + (c0 + j) * HW_);
#pragma unroll
        for (int j = 0; j < 16; j++) {
#pragma unroll
            for (int o = 0; o < 8; o++) {
                float w = wg[(ob + o) * 128 + c0 + j];   // uniform -> SGPR
                a[o].x = fmaf(w, v[j].x, a[o].x);
                a[o].y = fmaf(w, v[j].y, a[o].y);
            }
        }
    }
#pragma unroll
    for (int o = 0; o < 8; o++)
        *(float2*)(gg + (n * 16 + ob + o) * HW_ + s2) = a[o];
}

// ---------------------------------------------------------------------------
// K3: tap-parallel weight logits, scalar 1 px/thread, ZERO LDS.
// grid (576, 9). All weights/constants via uniform global reads (s_load).
// ---------------------------------------------------------------------------
struct WParams {
    const float *x1, *x2, *gg;
    const float *wp;
    const float *w1a, *w1b, *b1b, *w2a, *b2a;
    const float *prep;
    float *w1o, *w2o;   // [n][9][HW] raw logits
};

__global__ __launch_bounds__(256) void k_wtap_s(WParams P)
{
    const float* pr = P.prep;

    int k  = blockIdx.y;          // 0..8, uniform
    int ki = k / 3, kj = k - ki * 3;

    int p = blockIdx.x * 256 + threadIdx.x;
    int n = p / HW_, s = p - n * HW_;
    int hi = s / W_, wi = s - hi * W_;

    int hn = hi + ki - 1; hn = (hn < 0) ? -hn : ((hn >= H_) ? 2 * (H_ - 1) - hn : hn);
    int wn = wi + kj - 1; wn = (wn < 0) ? -wn : ((wn >= W_) ? 2 * (W_ - 1) - wn : wn);
    int snk = hn * W_ + wn;
    float dlh = (float)(hi - hn) * (2.0f / (H_ - 1));
    float dlw = (float)(wi - wn) * (2.0f / (W_ - 1));

    const float* x1p = P.x1 + n * (16 * HW_) + s;
    const float* x2p = P.x2 + n * (16 * HW_) + snk;
    const float* ggc = P.gg + n * (16 * HW_) + s;
    const float* ggn = P.gg + n * (16 * HW_) + snk;

    float h1[16];
#pragma unroll
    for (int o = 0; o < 16; o++) h1[o] = 0.0f;

#pragma unroll
    for (int c = 0; c < 16; c++) {
        float f = x1p[c * HW_] - x2p[c * HW_];
        f = fmaxf(fmaf(f, pr[c], pr[18 + c]), 0.0f);
#pragma unroll
        for (int o = 0; o < 16; o++) h1[o] = fmaf(P.w1a[o * 18 + c], f, h1[o]);
    }
#pragma unroll
    for (int pc = 0; pc < 2; pc++) {
        float f = P.wp[pc * 2 + 0] * dlw + P.wp[pc * 2 + 1] * dlh;
        f = fmaxf(fmaf(f, pr[16 + pc], pr[34 + pc]), 0.0f);
#pragma unroll
        for (int o = 0; o < 16; o++) h1[o] = fmaf(P.w1a[o * 18 + 16 + pc], f, h1[o]);
    }
    float l1 = P.b1b[0];
#pragma unroll
    for (int o = 0; o < 16; o++) {
        float v = fmaxf(fmaf(h1[o], pr[36 + o], pr[52 + o]), 0.0f);
        l1 = fmaf(P.w1b[o], v, l1);
    }

    float l2 = P.b2a[0];
#pragma unroll
    for (int c = 0; c < 16; c++) {
        float f = ggc[c * HW_] - ggn[c * HW_];
        f = fmaxf(fmaf(f, pr[68 + c], pr[84 + c]), 0.0f);
        l2 = fmaf(P.w2a[c], f, l2);
    }

    P.w1o[(n * 9 + k) * HW_ + s] = l1;
    P.w2o[(n * 9 + k) * HW_ + s] = l2;
}

// ---------------------------------------------------------------------------
// K4: pixel-vectorized 9-tap aggregation + in-register softmax.
// ---------------------------------------------------------------------------
__global__ __launch_bounds__(256) void k_agg4(
    const float* __restrict__ src, const float* __restrict__ wlog,
    float* __restrict__ dst)
{
    int tid = blockIdx.x * 256 + threadIdx.x;        // span id, 36864 total
    int cb  = blockIdx.y;
    int n   = tid / (HW_ / 4);
    int r   = tid - n * (HW_ / 4);
    int hi  = r / (W_ / 4);
    int w4  = (r - hi * (W_ / 4)) * 4;

    int h0 = (hi == 0) ? 1 : hi - 1;
    int h2 = (hi == H_ - 1) ? H_ - 2 : hi + 1;
    int rows0 = h0 * W_, rows1 = hi * W_, rows2 = h2 * W_;

    int offL = (w4 == 0)   ? 1   : w4 - 1;
    int offR = (w4 == 380) ? 382 : w4 + 4;

    const float* wl = wlog + n * 9 * HW_ + rows1 + w4;
    float4 wv[9];
#pragma unroll
    for (int k = 0; k < 9; k++) wv[k] = *(const float4*)(wl + k * HW_);
    float4 m = wv[0];
#pragma unroll
    for (int k = 1; k < 9; k++) {
        m.x = fmaxf(m.x, wv[k].x); m.y = fmaxf(m.y, wv[k].y);
        m.z = fmaxf(m.z, wv[k].z); m.w = fmaxf(m.w, wv[k].w);
    }
    float4 sum = make_float4(0.f, 0.f, 0.f, 0.f);
#pragma unroll
    for (int k = 0; k < 9; k++) {
        wv[k].x = __expf(wv[k].x - m.x); sum.x += wv[k].x;
        wv[k].y = __expf(wv[k].y - m.y); sum.y += wv[k].y;
        wv[k].z = __expf(wv[k].z - m.z); sum.z += wv[k].z;
        wv[k].w = __expf(wv[k].w - m.w); sum.w += wv[k].w;
    }
    float4 inv = make_float4(1.f / sum.x, 1.f / sum.y, 1.f / sum.z, 1.f / sum.w);
#pragma unroll
    for (int k = 0; k < 9; k++) {
        wv[k].x *= inv.x; wv[k].y *= inv.y; wv[k].z *= inv.z; wv[k].w *= inv.w;
    }

    const float* srcn = src + n * (64 * HW_);
    float* dstn = dst + n * (64 * HW_) + rows1 + w4;

#pragma unroll 4
    for (int ci = 0; ci < 16; ci++) {
        int c = cb * 16 + ci;
        const float* sp = srcn + c * HW_;
        float4 acc = make_float4(0.f, 0.f, 0.f, 0.f);
        int rr[3] = {rows0, rows1, rows2};
#pragma unroll
        for (int krow = 0; krow < 3; krow++) {
            const float* rowp = sp + rr[krow];
            float4 cv = *(const float4*)(rowp + w4);
            float  lf = rowp[offL];
            float  rt = rowp[offR];
            float4 wL = wv[krow * 3 + 0];
            float4 wC = wv[krow * 3 + 1];
            float4 wR = wv[krow * 3 + 2];
            acc.x = fmaf(wL.x, lf,   acc.x);
            acc.y = fmaf(wL.y, cv.x, acc.y);
            acc.z = fmaf(wL.z, cv.y, acc.z);
            acc.w = fmaf(wL.w, cv.z, acc.w);
            acc.x = fmaf(wC.x, cv.x, acc.x);
            acc.y = fmaf(wC.y, cv.y, acc.y);
            acc.z = fmaf(wC.z, cv.z, acc.z);
            acc.w = fmaf(wC.w, cv.w, acc.w);
            acc.x = fmaf(wR.x, cv.y, acc.x);
            acc.y = fmaf(wR.y, cv.z, acc.y);
            acc.z = fmaf(wR.z, cv.w, acc.z);
            acc.w = fmaf(wR.w, rt,   acc.w);
        }
        *(float4*)(dstn + c * HW_) = acc;
    }
}

// ---------------------------------------------------------------------------
extern "C" void kernel_launch(void* const* d_in, const int* in_sizes, int n_in,
                              void* d_out, int out_size, void* d_ws, size_t ws_size,
                              hipStream_t stream)
{
    const float* x    = (const float*)d_in[0];
    const float* g    = (const float*)d_in[1];
    const float* w_q  = (const float*)d_in[2];
    const float* b_q  = (const float*)d_in[3];
    const float* w_k  = (const float*)d_in[4];
    const float* b_k  = (const float*)d_in[5];
    const float* w_v  = (const float*)d_in[6];
    const float* b_v  = (const float*)d_in[7];
    const float* w_g  = (const float*)d_in[8];
    const float* b_g  = (const float*)d_in[9];
    const float* w_p  = (const float*)d_in[10];
    // d_in[11] = b_p (cancels in center-minus-neighbor subtraction)
    const float* bn1g = (const float*)d_in[12];
    const float* bn1b = (const float*)d_in[13];
    const float* bn1m = (const float*)d_in[14];
    const float* bn1v = (const float*)d_in[15];
    const float* w1a  = (const float*)d_in[16];
    const float* bn2g = (const float*)d_in[17];
    const float* bn2b = (const float*)d_in[18];
    const float* bn2m = (const float*)d_in[19];
    const float* bn2v = (const float*)d_in[20];
    const float* w1b  = (const float*)d_in[21];
    const float* b1b  = (const float*)d_in[22];
    const float* bn3g = (const float*)d_in[23];
    const float* bn3b = (const float*)d_in[24];
    const float* bn3m = (const float*)d_in[25];
    const float* bn3v = (const float*)d_in[26];
    const float* w2a  = (const float*)d_in[27];
    const float* b2a  = (const float*)d_in[28];

    float* ws    = (float*)d_ws;
    float* x1    = ws;                     // 2*16*HW = 2359296 f
    float* x2    = x1 + 2359296;           // 2359296 f
    float* gg    = x2 + 2359296;           // 2359296 f
    float* out1  = gg + 2359296;           // 2*64*HW = 9437184 f
    float* w1log = out1 + 9437184;         // 2*9*HW = 1327104 f
    float* w2log = w1log + 1327104;        // 1327104 f
    float* prep  = w2log + 1327104;        // 100 f  (total ~76.7 MB)
    float* x3    = (float*)d_out;          // d_out doubles as x3 scratch

    k_prep<<<1, 128, 0, stream>>>(bn1g, bn1b, bn1m, bn1v,
                                  bn2g, bn2b, bn2m, bn2v,
                                  bn3g, bn3b, bn3m, bn3v, prep);

    k_proj6<<<dim3(288, 6), 256, 0, stream>>>(x, w_q, b_q, w_k, b_k, w_v, b_v, x1, x2, x3);
    k_proj_g<<<dim3(288, 2), 256, 0, stream>>>(g, w_g, b_g, gg);

    WParams P;
    P.x1 = x1; P.x2 = x2; P.gg = gg;
    P.wp = w_p;
    P.w1a = w1a; P.w1b = w1b; P.b1b = b1b; P.w2a = w2a; P.b2a = b2a;
    P.prep = prep;
    P.w1o = w1log; P.w2o = w2log;
    k_wtap_s<<<dim3(576, 9), 256, 0, stream>>>(P);

    k_agg4<<<dim3(144, 4), 256, 0, stream>>>(x3, w1log, out1);            // agg1
    k_agg4<<<dim3(144, 4), 256, 0, stream>>>(out1, w2log, (float*)d_out); // agg2
}

// Round 9
// 139.715 us; speedup vs baseline: 3.4318x; 1.2086x over previous
//
#include <hip/hip_runtime.h>
#include <math.h>

#define H_ 192
#define W_ 384
#define HW_ 73728

// ---------------------------------------------------------------------------
// K1: all projections in one dispatch. grid (288, 4), 2 px/thread (float2).
// blockIdx.y: 0 = q+k (16+16 out from x), 1 = v[0:32], 2 = v[32:64],
//             3 = gg (16 out from g, single pass).
// Weights via uniform scalar loads (SGPR operands); batched prefetch arrays
// keep 4-8 loads in flight; accumulator shapes match the proven spill-free
// kernels (<= 64 f2-accum regs).
// ---------------------------------------------------------------------------
__global__ __launch_bounds__(256) void k_projall(
    const float* __restrict__ x, const float* __restrict__ g,
    const float* __restrict__ wq, const float* __restrict__ bq,
    const float* __restrict__ wk, const float* __restrict__ bk,
    const float* __restrict__ wv, const float* __restrict__ bv,
    const float* __restrict__ wg, const float* __restrict__ bg,
    float* __restrict__ x1, float* __restrict__ x2, float* __restrict__ x3,
    float* __restrict__ gg)
{
    int slab = blockIdx.y;
    int tid = blockIdx.x * 256 + threadIdx.x;   // 0..73727
    int n  = tid / (HW_ / 2);
    int s2 = (tid - n * (HW_ / 2)) * 2;

    if (slab == 0) {
        // ---- q + k ----
        float2 aq[16], ak[16];
#pragma unroll
        for (int o = 0; o < 16; o++) {
            float b0 = bq[o], b1 = bk[o];
            aq[o] = make_float2(b0, b0); ak[o] = make_float2(b1, b1);
        }
        const float* xp = x + n * (64 * HW_) + s2;
#pragma unroll 1
        for (int c0 = 0; c0 < 64; c0 += 4) {
            float2 v[4];
#pragma unroll
            for (int j = 0; j < 4; j++) v[j] = *(const float2*)(xp + (c0 + j) * HW_);
#pragma unroll
            for (int j = 0; j < 4; j++) {
#pragma unroll
                for (int o = 0; o < 16; o++) {
                    float w0 = wq[o * 64 + c0 + j];
                    float w1 = wk[o * 64 + c0 + j];
                    aq[o].x = fmaf(w0, v[j].x, aq[o].x);
                    aq[o].y = fmaf(w0, v[j].y, aq[o].y);
                    ak[o].x = fmaf(w1, v[j].x, ak[o].x);
                    ak[o].y = fmaf(w1, v[j].y, ak[o].y);
                }
            }
        }
        float* d1 = x1 + n * (16 * HW_) + s2;
        float* d2 = x2 + n * (16 * HW_) + s2;
#pragma unroll
        for (int o = 0; o < 16; o++) {
            *(float2*)(d1 + o * HW_) = aq[o];
            *(float2*)(d2 + o * HW_) = ak[o];
        }
    } else if (slab <= 2) {
        // ---- v half ----
        int q = slab - 1;
        const float* wsel = wv + q * 2048;
        const float* bsel = bv + q * 32;
        float2 av[32];
#pragma unroll
        for (int o = 0; o < 32; o++) { float b = bsel[o]; av[o] = make_float2(b, b); }
        const float* xp = x + n * (64 * HW_) + s2;
#pragma unroll 1
        for (int c0 = 0; c0 < 64; c0 += 4) {
            float2 v[4];
#pragma unroll
            for (int j = 0; j < 4; j++) v[j] = *(const float2*)(xp + (c0 + j) * HW_);
#pragma unroll
            for (int j = 0; j < 4; j++) {
#pragma unroll
                for (int o = 0; o < 32; o++) {
                    float w = wsel[o * 64 + c0 + j];
                    av[o].x = fmaf(w, v[j].x, av[o].x);
                    av[o].y = fmaf(w, v[j].y, av[o].y);
                }
            }
        }
        float* dst = x3 + (n * 64 + q * 32) * HW_ + s2;
#pragma unroll
        for (int o = 0; o < 32; o++) *(float2*)(dst + o * HW_) = av[o];
    } else {
        // ---- gg: all 16 outputs, single pass over g ----
        float2 a[16];
#pragma unroll
        for (int o = 0; o < 16; o++) { float b = bg[o]; a[o] = make_float2(b, b); }
        const float* gp = g + n * (128 * HW_) + s2;
#pragma unroll 1
        for (int c0 = 0; c0 < 128; c0 += 8) {
            float2 v[8];
#pragma unroll
            for (int j = 0; j < 8; j++) v[j] = *(const float2*)(gp + (c0 + j) * HW_);
#pragma unroll
            for (int j = 0; j < 8; j++) {
#pragma unroll
                for (int o = 0; o < 16; o++) {
                    float w = wg[o * 128 + c0 + j];
                    a[o].x = fmaf(w, v[j].x, a[o].x);
                    a[o].y = fmaf(w, v[j].y, a[o].y);
                }
            }
        }
        float* dst = gg + n * (16 * HW_) + s2;
#pragma unroll
        for (int o = 0; o < 16; o++) *(float2*)(dst + o * HW_) = a[o];
    }
}

// ---------------------------------------------------------------------------
// K2: tap-parallel weight logits, scalar 1 px/thread, ZERO LDS.
// grid (576, 9). BN folding inlined (uniform scalar math). All weights via
// uniform global reads (s_load).
// ---------------------------------------------------------------------------
struct WParams {
    const float *x1, *x2, *gg;
    const float *wp;
    const float *w1a, *w1b, *b1b, *w2a, *b2a;
    const float *bn1g, *bn1b, *bn1m, *bn1v;
    const float *bn2g, *bn2b, *bn2m, *bn2v;
    const float *bn3g, *bn3b, *bn3m, *bn3v;
    float *w1o, *w2o;   // [n][9][HW] raw logits
};

__global__ __launch_bounds__(256) void k_wtap_s(WParams P)
{
    int k  = blockIdx.y;          // 0..8, uniform
    int ki = k / 3, kj = k - ki * 3;

    int p = blockIdx.x * 256 + threadIdx.x;
    int n = p / HW_, s = p - n * HW_;
    int hi = s / W_, wi = s - hi * W_;

    int hn = hi + ki - 1; hn = (hn < 0) ? -hn : ((hn >= H_) ? 2 * (H_ - 1) - hn : hn);
    int wn = wi + kj - 1; wn = (wn < 0) ? -wn : ((wn >= W_) ? 2 * (W_ - 1) - wn : wn);
    int snk = hn * W_ + wn;
    float dlh = (float)(hi - hn) * (2.0f / (H_ - 1));
    float dlw = (float)(wi - wn) * (2.0f / (W_ - 1));

    const float* x1p = P.x1 + n * (16 * HW_) + s;
    const float* x2p = P.x2 + n * (16 * HW_) + snk;
    const float* ggc = P.gg + n * (16 * HW_) + s;
    const float* ggn = P.gg + n * (16 * HW_) + snk;

    float h1[16];
#pragma unroll
    for (int o = 0; o < 16; o++) h1[o] = 0.0f;

#pragma unroll
    for (int c = 0; c < 16; c++) {
        float sc = P.bn1g[c] * rsqrtf(P.bn1v[c] + 1e-5f);
        float tc = P.bn1b[c] - P.bn1m[c] * sc;
        float f = x1p[c * HW_] - x2p[c * HW_];
        f = fmaxf(fmaf(f, sc, tc), 0.0f);
#pragma unroll
        for (int o = 0; o < 16; o++) h1[o] = fmaf(P.w1a[o * 18 + c], f, h1[o]);
    }
#pragma unroll
    for (int pc = 0; pc < 2; pc++) {
        float sc = P.bn1g[16 + pc] * rsqrtf(P.bn1v[16 + pc] + 1e-5f);
        float tc = P.bn1b[16 + pc] - P.bn1m[16 + pc] * sc;
        float f = P.wp[pc * 2 + 0] * dlw + P.wp[pc * 2 + 1] * dlh;
        f = fmaxf(fmaf(f, sc, tc), 0.0f);
#pragma unroll
        for (int o = 0; o < 16; o++) h1[o] = fmaf(P.w1a[o * 18 + 16 + pc], f, h1[o]);
    }
    float l1 = P.b1b[0];
#pragma unroll
    for (int o = 0; o < 16; o++) {
        float sc = P.bn2g[o] * rsqrtf(P.bn2v[o] + 1e-5f);
        float tc = P.bn2b[o] - P.bn2m[o] * sc;
        float v = fmaxf(fmaf(h1[o], sc, tc), 0.0f);
        l1 = fmaf(P.w1b[o], v, l1);
    }

    float l2 = P.b2a[0];
#pragma unroll
    for (int c = 0; c < 16; c++) {
        float sc = P.bn3g[c] * rsqrtf(P.bn3v[c] + 1e-5f);
        float tc = P.bn3b[c] - P.bn3m[c] * sc;
        float f = ggc[c * HW_] - ggn[c * HW_];
        f = fmaxf(fmaf(f, sc, tc), 0.0f);
        l2 = fmaf(P.w2a[c], f, l2);
    }

    P.w1o[(n * 9 + k) * HW_ + s] = l1;
    P.w2o[(n * 9 + k) * HW_ + s] = l2;
}

// ---------------------------------------------------------------------------
// K3: pixel-vectorized 9-tap aggregation + in-register softmax.
// grid (144, 8): 8-channel slabs -> 1152 blocks for latency hiding.
// ---------------------------------------------------------------------------
__global__ __launch_bounds__(256) void k_agg4(
    const float* __restrict__ src, const float* __restrict__ wlog,
    float* __restrict__ dst)
{
    int tid = blockIdx.x * 256 + threadIdx.x;        // span id, 36864 total
    int cb  = blockIdx.y;
    int n   = tid / (HW_ / 4);
    int r   = tid - n * (HW_ / 4);
    int hi  = r / (W_ / 4);
    int w4  = (r - hi * (W_ / 4)) * 4;

    int h0 = (hi == 0) ? 1 : hi - 1;
    int h2 = (hi == H_ - 1) ? H_ - 2 : hi + 1;
    int rows0 = h0 * W_, rows1 = hi * W_, rows2 = h2 * W_;

    int offL = (w4 == 0)   ? 1   : w4 - 1;
    int offR = (w4 == 380) ? 382 : w4 + 4;

    const float* wl = wlog + n * 9 * HW_ + rows1 + w4;
    float4 wv[9];
#pragma unroll
    for (int k = 0; k < 9; k++) wv[k] = *(const float4*)(wl + k * HW_);
    float4 m = wv[0];
#pragma unroll
    for (int k = 1; k < 9; k++) {
        m.x = fmaxf(m.x, wv[k].x); m.y = fmaxf(m.y, wv[k].y);
        m.z = fmaxf(m.z, wv[k].z); m.w = fmaxf(m.w, wv[k].w);
    }
    float4 sum = make_float4(0.f, 0.f, 0.f, 0.f);
#pragma unroll
    for (int k = 0; k < 9; k++) {
        wv[k].x = __expf(wv[k].x - m.x); sum.x += wv[k].x;
        wv[k].y = __expf(wv[k].y - m.y); sum.y += wv[k].y;
        wv[k].z = __expf(wv[k].z - m.z); sum.z += wv[k].z;
        wv[k].w = __expf(wv[k].w - m.w); sum.w += wv[k].w;
    }
    float4 inv = make_float4(1.f / sum.x, 1.f / sum.y, 1.f / sum.z, 1.f / sum.w);
#pragma unroll
    for (int k = 0; k < 9; k++) {
        wv[k].x *= inv.x; wv[k].y *= inv.y; wv[k].z *= inv.z; wv[k].w *= inv.w;
    }

    const float* srcn = src + n * (64 * HW_);
    float* dstn = dst + n * (64 * HW_) + rows1 + w4;

#pragma unroll
    for (int ci = 0; ci < 8; ci++) {
        int c = cb * 8 + ci;
        const float* sp = srcn + c * HW_;
        float4 acc = make_float4(0.f, 0.f, 0.f, 0.f);
        int rr[3] = {rows0, rows1, rows2};
#pragma unroll
        for (int krow = 0; krow < 3; krow++) {
            const float* rowp = sp + rr[krow];
            float4 cv = *(const float4*)(rowp + w4);
            float  lf = rowp[offL];
            float  rt = rowp[offR];
            float4 wL = wv[krow * 3 + 0];
            float4 wC = wv[krow * 3 + 1];
            float4 wR = wv[krow * 3 + 2];
            acc.x = fmaf(wL.x, lf,   acc.x);
            acc.y = fmaf(wL.y, cv.x, acc.y);
            acc.z = fmaf(wL.z, cv.y, acc.z);
            acc.w = fmaf(wL.w, cv.z, acc.w);
            acc.x = fmaf(wC.x, cv.x, acc.x);
            acc.y = fmaf(wC.y, cv.y, acc.y);
            acc.z = fmaf(wC.z, cv.z, acc.z);
            acc.w = fmaf(wC.w, cv.w, acc.w);
            acc.x = fmaf(wR.x, cv.y, acc.x);
            acc.y = fmaf(wR.y, cv.z, acc.y);
            acc.z = fmaf(wR.z, cv.w, acc.z);
            acc.w = fmaf(wR.w, rt,   acc.w);
        }
        *(float4*)(dstn + c * HW_) = acc;
    }
}

// ---------------------------------------------------------------------------
extern "C" void kernel_launch(void* const* d_in, const int* in_sizes, int n_in,
                              void* d_out, int out_size, void* d_ws, size_t ws_size,
                              hipStream_t stream)
{
    const float* x    = (const float*)d_in[0];
    const float* g    = (const float*)d_in[1];
    const float* w_q  = (const float*)d_in[2];
    const float* b_q  = (const float*)d_in[3];
    const float* w_k  = (const float*)d_in[4];
    const float* b_k  = (const float*)d_in[5];
    const float* w_v  = (const float*)d_in[6];
    const float* b_v  = (const float*)d_in[7];
    const float* w_g  = (const float*)d_in[8];
    const float* b_g  = (const float*)d_in[9];
    const float* w_p  = (const float*)d_in[10];
    // d_in[11] = b_p (cancels in center-minus-neighbor subtraction)
    const float* bn1g = (const float*)d_in[12];
    const float* bn1b = (const float*)d_in[13];
    const float* bn1m = (const float*)d_in[14];
    const float* bn1v = (const float*)d_in[15];
    const float* w1a  = (const float*)d_in[16];
    const float* bn2g = (const float*)d_in[17];
    const float* bn2b = (const float*)d_in[18];
    const float* bn2m = (const float*)d_in[19];
    const float* bn2v = (const float*)d_in[20];
    const float* w1b  = (const float*)d_in[21];
    const float* b1b  = (const float*)d_in[22];
    const float* bn3g = (const float*)d_in[23];
    const float* bn3b = (const float*)d_in[24];
    const float* bn3m = (const float*)d_in[25];
    const float* bn3v = (const float*)d_in[26];
    const float* w2a  = (const float*)d_in[27];
    const float* b2a  = (const float*)d_in[28];

    float* ws    = (float*)d_ws;
    float* x1    = ws;                     // 2*16*HW = 2359296 f
    float* x2    = x1 + 2359296;           // 2359296 f
    float* gg    = x2 + 2359296;           // 2359296 f
    float* out1  = gg + 2359296;           // 2*64*HW = 9437184 f
    float* w1log = out1 + 9437184;         // 2*9*HW = 1327104 f
    float* w2log = w1log + 1327104;        // 1327104 f  (total ~76.7 MB)
    float* x3    = (float*)d_out;          // d_out doubles as x3 scratch

    k_projall<<<dim3(288, 4), 256, 0, stream>>>(x, g, w_q, b_q, w_k, b_k,
                                                w_v, b_v, w_g, b_g,
                                                x1, x2, x3, gg);

    WParams P;
    P.x1 = x1; P.x2 = x2; P.gg = gg;
    P.wp = w_p;
    P.w1a = w1a; P.w1b = w1b; P.b1b = b1b; P.w2a = w2a; P.b2a = b2a;
    P.bn1g = bn1g; P.bn1b = bn1b; P.bn1m = bn1m; P.bn1v = bn1v;
    P.bn2g = bn2g; P.bn2b = bn2b; P.bn2m = bn2m; P.bn2v = bn2v;
    P.bn3g = bn3g; P.bn3b = bn3b; P.bn3m = bn3m; P.bn3v = bn3v;
    P.w1o = w1log; P.w2o = w2log;
    k_wtap_s<<<dim3(576, 9), 256, 0, stream>>>(P);

    k_agg4<<<dim3(144, 8), 256, 0, stream>>>(x3, w1log, out1);            // agg1
    k_agg4<<<dim3(144, 8), 256, 0, stream>>>(out1, w2log, (float*)d_out); // agg2
}